// Round 3
// baseline (300.743 us; speedup 1.0000x reference)
//
#include <hip/hip_runtime.h>

// CosformerAttention on MI355X (gfx950). Inputs fp32, OUTPUT fp32.
// B=8, E=768, L=48*48=2304, heads=12, d=64, n=B*h=96, M=L*B=18432.
//
// Round-10: timed total (297us) is insensitive to profiled gemm gains =>
// critical path is the unprofiled kernels + launch overhead. Changes:
//  - kv_mfma: swapped MFMA operands -> writes kvT[n][m][j] (m-major), ksum
//    via f32 register accumulation + LDS reduce (ones-tile dropped).
//  - attn_mfma: Bs staging becomes coalesced float4 + ds_write_b64 (was 32
//    stride-128B scalar loads + 32 ds_write_u16 per thread).
//  - conv_w + transpose_q + kv/ksum memset merged into one `prep` kernel:
//    7 -> 5 launches.
//  - gemm256 unchanged from round-9 (83us profiled, MfmaUtil 32%, 0 conflicts).

#define L_SEQ 2304
#define BATCH 8
#define EDIM 768
#define NHEAD 12
#define DHEAD 64
#define MROWS (L_SEQ * BATCH)  // 18432

typedef __attribute__((ext_vector_type(8))) short bf16x8_t;   // 8 bf16 = 4 VGPRs
typedef __attribute__((ext_vector_type(4))) float f32x4_t;

__device__ __forceinline__ float b2f(unsigned short u) {
  union { unsigned int i; float f; } x; x.i = ((unsigned int)u) << 16; return x.f;
}
__device__ __forceinline__ unsigned short f2b(float f) {
  union { float f; unsigned int i; } x; x.f = f;
  unsigned int r = x.i + 0x7FFFu + ((x.i >> 16) & 1u);  // RNE
  return (unsigned short)(r >> 16);
}

// async 16B global->LDS (gfx950; wave-uniform base + lane*16 dest contract)
#define GLOAD_LDS16(g, l)                                                     \
  __builtin_amdgcn_global_load_lds(                                           \
      (const __attribute__((address_space(1))) unsigned int*)(g),             \
      (__attribute__((address_space(3))) unsigned int*)(l), 16, 0, 0)

// ---------------------------------------------------------------------------
// Kernel 0 (merged): blocks [0,2304): conv 4 fp32 weight mats -> bf16.
//                    blocks [2304,5760): transpose query (B,E,L) -> xT bf16.
//                    blocks [5760,6540): zero kv (3,145,728 B) + ksum (49,152 B).
__global__ __launch_bounds__(256) void prep(
    const float* __restrict__ q,
    const float* __restrict__ W0, const float* __restrict__ W1,
    const float* __restrict__ W2, const float* __restrict__ W3,
    unsigned short* __restrict__ wbf, unsigned short* __restrict__ xT,
    float* __restrict__ kvz) {
  __shared__ float tile[64][65];
  int bx = blockIdx.x;
  int t = threadIdx.x;
  if (bx < 2304) {
    int y = bx / 576;
    const float* W = (y == 0) ? W0 : (y == 1) ? W1 : (y == 2) ? W2 : W3;
    unsigned short* d = wbf + (size_t)y * EDIM * EDIM;
    int idx = (bx - y * 576) * 256 + t;  // [0, 147456)
    float4 v = *(const float4*)(W + (size_t)idx * 4);
    ushort4 o;
    o.x = f2b(v.x); o.y = f2b(v.y); o.z = f2b(v.z); o.w = f2b(v.w);
    *(ushort4*)(d + (size_t)idx * 4) = o;
  } else if (bx < 5760) {
    int bb = bx - 2304;           // 12 x 36 x 8
    int e0 = (bb % 12) * 64;
    int l0 = ((bb / 12) % 36) * 64;
    int b = bb / 432;
    int li = t & 63, er = t >> 6;
#pragma unroll
    for (int p = 0; p < 16; p++) {
      int eo = er + p * 4;
      tile[eo][li] = q[((size_t)b * EDIM + (e0 + eo)) * L_SEQ + (l0 + li)];
    }
    __syncthreads();
    int ei = t & 63, lr = t >> 6;
#pragma unroll
    for (int p = 0; p < 16; p++) {
      int lo = lr + p * 4;
      xT[((size_t)b * L_SEQ + (l0 + lo)) * EDIM + (e0 + ei)] = f2b(tile[ei][lo]);
    }
  } else {
    int idx = (bx - 5760) * 256 + t;  // [0, 199680) float4s
    *(float4*)(kvz + (size_t)idx * 4) = make_float4(0.f, 0.f, 0.f, 0.f);
  }
}

// ---------------------------------------------------------------------------
// Kernel 1/4: C = A @ W^T (+bias, opt relu). 256x256 tile, BK=64, 512 thr
// (8 waves, 2Mx4N), 8-phase pipelined K-loop, 128 KiB dynamic LDS.
// (unchanged from round-9; see schedule comments there)
#define ALDSO(b_, h_) ((b_) * 16384 + (h_) * 8192)
#define BLDSO(b_, h_) (32768 + (b_) * 16384 + (h_) * 8192)

#define BAR() __builtin_amdgcn_s_barrier()
#define LGKM0() asm volatile("s_waitcnt lgkmcnt(0)")
#define LGKM8() asm volatile("s_waitcnt lgkmcnt(8)")
#define VMW(N) asm volatile("s_waitcnt vmcnt(" #N ")" ::: "memory")

#define STG_A(h_, kt_, LB_)                                                          \
  {                                                                                  \
    GLOAD_LDS16(a_sb + (size_t)((h_) * 128) * EDIM + (kt_) * 64, lds + (LB_) + t * 8); \
    GLOAD_LDS16(a_sb + (size_t)((h_) * 128 + 64) * EDIM + (kt_) * 64,                \
                lds + (LB_) + 4096 + t * 8);                                         \
  }
#define STG_B(h_, kt_, LB_)                                                          \
  {                                                                                  \
    GLOAD_LDS16(b_sb + (size_t)((h_) * 128) * EDIM + (kt_) * 64, lds + (LB_) + t * 8); \
    GLOAD_LDS16(b_sb + (size_t)((h_) * 128 + 64) * EDIM + (kt_) * 64,                \
                lds + (LB_) + 4096 + t * 8);                                         \
  }

#define DS_A(SET, B_, H_)                                                            \
  _Pragma("unroll") for (int i_ = 0; i_ < 4; i_++)                                   \
  _Pragma("unroll") for (int kk_ = 0; kk_ < 2; kk_++)                                \
    SET[i_][kk_] = *(const bf16x8_t*)(lds + ALDSO(B_, H_) +                          \
                                      ((a_base + i_ * 1024 + kk_ * 32) ^ xorv));

#define DS_B(SET, B_, H_)                                                            \
  _Pragma("unroll") for (int j_ = 0; j_ < 2; j_++)                                   \
  _Pragma("unroll") for (int kk_ = 0; kk_ < 2; kk_++)                                \
    SET[j_][kk_] = *(const bf16x8_t*)(lds + BLDSO(B_, H_) +                          \
                                      ((b_base + j_ * 1024 + kk_ * 32) ^ xorv));

#define MFMAQ(ASET, BSET, AH, BH)                                                    \
  __builtin_amdgcn_s_setprio(1);                                                     \
  _Pragma("unroll") for (int i_ = 0; i_ < 4; i_++)                                   \
  _Pragma("unroll") for (int j_ = 0; j_ < 2; j_++)                                   \
  _Pragma("unroll") for (int kk_ = 0; kk_ < 2; kk_++)                                \
    acc[(AH) * 4 + i_][(BH) * 2 + j_] = __builtin_amdgcn_mfma_f32_16x16x32_bf16(     \
        ASET[i_][kk_], BSET[j_][kk_], acc[(AH) * 4 + i_][(BH) * 2 + j_], 0, 0, 0);   \
  __builtin_amdgcn_s_setprio(0);

template <int MODE>
__global__ __launch_bounds__(512, 2) void gemm256(
    const unsigned short* __restrict__ A,
    const unsigned short* __restrict__ Wall,
    const float* __restrict__ bias0, const float* __restrict__ bias1,
    const float* __restrict__ bias2,
    unsigned short* __restrict__ dst0, unsigned short* __restrict__ dst1,
    unsigned short* __restrict__ dst2,
    float* __restrict__ dstf) {
  extern __shared__ __align__(16) unsigned short lds[];

  const unsigned short* W;
  const float* bias;
  unsigned short* dst = nullptr;
  bool do_relu = false;
  int rowblk, colblk;
  {
    int nwg = (int)gridDim.x;
    int wg = ((int)blockIdx.x & 7) * (nwg >> 3) + ((int)blockIdx.x >> 3);
    if (MODE == 0) {
      rowblk = wg / 9;
      int c = wg - rowblk * 9;
      colblk = c % 3;
      int z = c / 3;
      W = Wall + (size_t)z * EDIM * EDIM;
      bias = (z == 0) ? bias0 : (z == 1) ? bias1 : bias2;
      dst = (z == 0) ? dst0 : (z == 1) ? dst1 : dst2;
      do_relu = (z < 2);
    } else {
      rowblk = wg / 3;
      colblk = wg - rowblk * 3;
      W = Wall;
      bias = bias0;
    }
  }
  const int row0 = rowblk * 256;
  const int col0 = colblk * 256;

  const int t = threadIdx.x;
  const int lane = t & 63;
  const int wave = t >> 6;
  const int wm = wave >> 2;
  const int wn = wave & 3;
  const int mrow = lane & 15;
  const int quad = lane >> 4;

  const int xorv = (mrow & 7) << 3;
  const int a_base = (wm * 64 + mrow) * 64 + quad * 8;
  const int b_base = (wn * 32 + mrow) * 64 + quad * 8;

  const int lr_s = t >> 3;
  const int k0_s = ((((t >> 3) & 7) ^ (t & 7)) << 3);
  const unsigned short* a_sb = A + (size_t)(row0 + lr_s) * EDIM + k0_s;
  const unsigned short* b_sb = W + (size_t)(col0 + lr_s) * EDIM + k0_s;

  f32x4_t acc[8][4] = {};
  bf16x8_t aA[4][2], aB[4][2], bA[2][2], bB[2][2];

  STG_A(0, 0, ALDSO(0, 0));
  STG_B(0, 0, BLDSO(0, 0));
  STG_A(1, 0, ALDSO(0, 1));
  STG_B(1, 0, BLDSO(0, 1));
  STG_A(0, 1, ALDSO(1, 0));
  STG_B(0, 1, BLDSO(1, 0));
  VMW(4);
  BAR();

#pragma unroll
  for (int i = 0; i < 6; ++i) {
    const int kt0 = 2 * i, kt1 = 2 * i + 1;
    const bool nxt = (i < 5);
    // ph1
    DS_A(aA, 0, 0);
    DS_B(bA, 0, 0);
    STG_A(1, kt1, ALDSO(1, 1));
    LGKM8();
    BAR();
    MFMAQ(aA, bA, 0, 0);
    LGKM0();
    BAR();
    // ph2
    DS_B(bB, 0, 1);
    STG_B(1, kt1, BLDSO(1, 1));
    BAR();
    MFMAQ(aA, bB, 0, 1);
    LGKM0();
    BAR();
    // ph3
    DS_A(aB, 0, 1);
    if (nxt) STG_A(0, kt0 + 2, ALDSO(0, 0));
    BAR();
    MFMAQ(aB, bA, 1, 0);
    LGKM0();
    BAR();
    // ph4
    if (nxt) STG_B(0, kt0 + 2, BLDSO(0, 0));
    BAR();
    MFMAQ(aB, bB, 1, 1);
    if (nxt) { VMW(4); } else { VMW(0); }
    BAR();
    // ph5
    DS_A(aA, 1, 0);
    DS_B(bA, 1, 0);
    if (nxt) STG_A(1, kt0 + 2, ALDSO(0, 1));
    LGKM8();
    BAR();
    MFMAQ(aA, bA, 0, 0);
    LGKM0();
    BAR();
    // ph6
    DS_B(bB, 1, 1);
    if (nxt) STG_B(1, kt0 + 2, BLDSO(0, 1));
    BAR();
    MFMAQ(aA, bB, 0, 1);
    LGKM0();
    BAR();
    // ph7
    DS_A(aB, 1, 1);
    if (nxt) STG_A(0, kt1 + 2, ALDSO(1, 0));
    BAR();
    MFMAQ(aB, bA, 1, 0);
    LGKM0();
    BAR();
    // ph8
    if (nxt) STG_B(0, kt1 + 2, BLDSO(1, 0));
    BAR();
    MFMAQ(aB, bB, 1, 1);
    if (nxt) { VMW(4); } else { VMW(0); }
    BAR();
  }

  const int bb = row0 / L_SEQ;
#pragma unroll
  for (int ti = 0; ti < 8; ti++) {
    int rbase = row0 + (ti >> 2) * 128 + wm * 64 + (ti & 3) * 16 + quad * 4;
#pragma unroll
    for (int tj = 0; tj < 4; tj++) {
      int gc = col0 + (tj >> 1) * 128 + wn * 32 + (tj & 1) * 16 + mrow;
      float bv = bias[gc];
#pragma unroll
      for (int r = 0; r < 4; r++) {
        int gr = rbase + r;
        float v = acc[ti][tj][r] + bv;
        if (MODE == 0) {
          if (do_relu) v = fmaxf(v, 0.0f);
          int ll = gr - bb * L_SEQ;
          int n = bb * NHEAD + (gc >> 6);
          dst[((size_t)n * L_SEQ + ll) * DHEAD + (gc & 63)] = f2b(v);
        } else {
          dstf[(size_t)gr * EDIM + gc] = v;  // FP32 output
        }
      }
    }
  }
}

// ---------------------------------------------------------------------------
// Kernel 2 (MFMA): kvT[n][m][j] = sum_l v[l][m]*k_[l][j]; ksum[n][j] = sum_l k_.
// Swapped operands vs round-9: A = v-tile (m rows), B = k-tile (j cols) =>
// D[m][j] lands m-major, so attn's Bs staging reads kvT rows coalesced.
// ksum via f32 register accumulation + LDS-atomic reduce (ones-tile dropped).
__global__ __launch_bounds__(256) void kv_mfma(
    const unsigned short* __restrict__ kbuf, const unsigned short* __restrict__ vbuf,
    float* __restrict__ kvT, float* __restrict__ ksum) {
  constexpr int ST = 40;  // LDS row stride (bf16)
  __shared__ __align__(16) unsigned short ksT[128 * ST];
  __shared__ __align__(16) unsigned short vsT[64 * ST];
  __shared__ float ksum_l[128];
  int n = blockIdx.x;
  int lbase = blockIdx.y * 288;
  int t = threadIdx.x;
  int lane = t & 63, wave = t >> 6;
  int mrow = lane & 15, quad = lane >> 4;

  if (t < 128) ksum_l[t] = 0.f;

  int lrd = t >> 3;   // l within slice, 0..31
  int oct = t & 7;    // d-octet
  const unsigned short* kbase = kbuf + (size_t)n * L_SEQ * DHEAD + oct * 8;
  const unsigned short* vbase = vbuf + (size_t)n * L_SEQ * DHEAD + oct * 8;

  f32x4_t acc[8] = {};
  float sks[8] = {}, skc[8] = {};

  for (int s = 0; s < 9; s++) {
    int l = lbase + s * 32 + lrd;
    float sv, cv;
    sincosf(1.5707963267948966f * (float)(l + 1) / 2304.0f, &sv, &cv);
    union { uint4 q; unsigned short u[8]; } kq, vq;
    kq.q = *(const uint4*)(kbase + (size_t)l * DHEAD);
    vq.q = *(const uint4*)(vbase + (size_t)l * DHEAD);
    __syncthreads();  // previous slice's fragment reads done (also covers ksum_l init)
#pragma unroll
    for (int e = 0; e < 8; e++) {
      int d = oct * 8 + e;
      float kval = b2f(kq.u[e]);
      float a = kval * sv, c = kval * cv;
      ksT[d * ST + lrd] = f2b(a);
      ksT[(64 + d) * ST + lrd] = f2b(c);
      vsT[d * ST + lrd] = vq.u[e];
      sks[e] += a;
      skc[e] += c;
    }
    __syncthreads();
    // A-frag: lane (mrow,quad) holds vsT[m=wave*16+mrow][l=quad*8..+8] = v[l][m]
    bf16x8_t af = *(const bf16x8_t*)(vsT + (wave * 16 + mrow) * ST + quad * 8);
#pragma unroll
    for (int jt = 0; jt < 8; jt++) {
      // B-frag: lane holds ksT[j=jt*16+mrow][l=quad*8..+8] = k_[l][j]
      bf16x8_t bfk = *(const bf16x8_t*)(ksT + (jt * 16 + mrow) * ST + quad * 8);
      acc[jt] = __builtin_amdgcn_mfma_f32_16x16x32_bf16(af, bfk, acc[jt], 0, 0, 0);
    }
  }

  // ksum reduce: per-thread f32 partials -> LDS -> global
#pragma unroll
  for (int e = 0; e < 8; e++) {
    atomicAdd(&ksum_l[oct * 8 + e], sks[e]);
    atomicAdd(&ksum_l[64 + oct * 8 + e], skc[e]);
  }
  __syncthreads();
  if (t < 128) atomicAdd(&ksum[n * 128 + t], ksum_l[t]);

  // kvT epilogue: D col = mrow -> j, row = quad*4+r -> m (within wave's m-tile)
#pragma unroll
  for (int jt = 0; jt < 8; jt++) {
#pragma unroll
    for (int r = 0; r < 4; r++) {
      int m = wave * 16 + quad * 4 + r;
      int j = jt * 16 + mrow;
      atomicAdd(&kvT[((size_t)n * 64 + m) * 128 + j], acc[jt][r]);
    }
  }
}

// ---------------------------------------------------------------------------
// Kernel 3 (MFMA): C0 = q@kv0, C1 = q@kv1; out = zs*C0 + zc*C1; fused
// residual + relayout. grid (18, 96), block 256. Bs staged from kvT rows
// (coalesced float4 + vectorized LDS writes).
__global__ __launch_bounds__(256) void attn_mfma(
    const unsigned short* __restrict__ qbuf, const float* __restrict__ kvT,
    const float* __restrict__ ksum, const unsigned short* __restrict__ xT,
    unsigned short* __restrict__ attn) {
  __shared__ __align__(16) unsigned short As[128 * 72];
  __shared__ __align__(16) unsigned short Bs[64 * 136];
  __shared__ float ks_l[128];
  __shared__ float zs[128], zc[128];
  int l0 = blockIdx.x * 128;
  int n = blockIdx.y;
  int t = threadIdx.x;
  int lane = t & 63, wave = t >> 6;
  int mrow = lane & 15, quad = lane >> 4;
  int b = n / NHEAD, hd = n % NHEAD;

  {
    int row = t >> 1, off = (t & 1) * 32;
    const unsigned short* src = qbuf + ((size_t)n * L_SEQ + l0 + row) * DHEAD + off;
    unsigned short* d = As + row * 72 + off;
#pragma unroll
    for (int c = 0; c < 4; c++)
      *(uint4*)(d + c * 8) = *(const uint4*)(src + c * 8);
  }
  {
    int m = t >> 2, part = t & 3;  // Bs[m][j] = f2b(kvT[n][m][j]) -- coalesced
    const float* src = kvT + ((size_t)n * 64 + m) * 128 + part * 32;
    unsigned short* dBs = Bs + m * 136 + part * 32;
#pragma unroll
    for (int c = 0; c < 4; c++) {
      float4 a = *(const float4*)(src + c * 8);
      float4 bq = *(const float4*)(src + c * 8 + 4);
      ushort4 o1, o2;
      o1.x = f2b(a.x); o1.y = f2b(a.y); o1.z = f2b(a.z); o1.w = f2b(a.w);
      o2.x = f2b(bq.x); o2.y = f2b(bq.y); o2.z = f2b(bq.z); o2.w = f2b(bq.w);
      *(ushort4*)(dBs + c * 8) = o1;
      *(ushort4*)(dBs + c * 8 + 4) = o2;
    }
  }
  if (t < 128) ks_l[t] = ksum[n * 128 + t];
  __syncthreads();

  if (t < 128) {
    float d0 = 0.f, d1 = 0.f;
    const unsigned short* arow = As + t * 72;
#pragma unroll
    for (int j = 0; j < 8; j++) {
      bf16x8_t v = *(const bf16x8_t*)(arow + j * 8);
#pragma unroll
      for (int e = 0; e < 8; e++) {
        float qv = b2f((unsigned short)v[e]);
        d0 += qv * ks_l[j * 8 + e];
        d1 += qv * ks_l[64 + j * 8 + e];
      }
    }
    float sv, cv;
    sincosf(1.5707963267948966f * (float)(l0 + t + 1) / 2304.0f, &sv, &cv);
    float z = 1.0f / fmaxf(sv * d0 + cv * d1, 1e-6f);
    zs[t] = z * sv;
    zc[t] = z * cv;
  }
  __syncthreads();

  int wr = wave * 32;
  f32x4_t acc0[2][4] = {}, acc1[2][4] = {};
#pragma unroll
  for (int ks = 0; ks < 2; ks++) {
    bf16x8_t af[2];
#pragma unroll
    for (int ti = 0; ti < 2; ti++)
      af[ti] = *(const bf16x8_t*)(As + (wr + ti * 16 + mrow) * 72 + ks * 32 + quad * 8);
#pragma unroll
    for (int tj = 0; tj < 4; tj++) {
      bf16x8_t b0 = *(const bf16x8_t*)(Bs + (tj * 16 + mrow) * 136 + ks * 32 + quad * 8);
      bf16x8_t b1 = *(const bf16x8_t*)(Bs + (tj * 16 + mrow) * 136 + 64 + ks * 32 + quad * 8);
#pragma unroll
      for (int ti = 0; ti < 2; ti++) {
        acc0[ti][tj] = __builtin_amdgcn_mfma_f32_16x16x32_bf16(af[ti], b0, acc0[ti][tj], 0, 0, 0);
        acc1[ti][tj] = __builtin_amdgcn_mfma_f32_16x16x32_bf16(af[ti], b1, acc1[ti][tj], 0, 0, 0);
      }
    }
  }

#pragma unroll
  for (int ti = 0; ti < 2; ti++) {
#pragma unroll
    for (int tj = 0; tj < 4; tj++) {
      int m = tj * 16 + mrow;
#pragma unroll
      for (int r = 0; r < 4; r++) {
        int row = wr + ti * 16 + quad * 4 + r;
        int l = l0 + row;
        float ov = zs[row] * acc0[ti][tj][r] + zc[row] * acc1[ti][tj][r];
        float xv = b2f(xT[((size_t)b * L_SEQ + l) * EDIM + hd * DHEAD + m]);
        attn[((size_t)l * BATCH + b) * EDIM + hd * DHEAD + m] = f2b(xv + ov);
      }
    }
  }
}

// ---------------------------------------------------------------------------
extern "C" void kernel_launch(void* const* d_in, const int* in_sizes, int n_in,
                              void* d_out, int out_size, void* d_ws, size_t ws_size,
                              hipStream_t stream) {
  const float* query = (const float*)d_in[0];
  const float* Wq = (const float*)d_in[1];
  const float* bq = (const float*)d_in[2];
  const float* Wk = (const float*)d_in[3];
  const float* bk = (const float*)d_in[4];
  const float* Wv = (const float*)d_in[5];
  const float* bv = (const float*)d_in[6];
  const float* Wo = (const float*)d_in[7];
  const float* bo = (const float*)d_in[8];
  float* out = (float*)d_out;  // fp32 output

  unsigned short* xT = (unsigned short*)d_out;  // bf16 staging inside d_out

  char* ws = (char*)d_ws;
  const size_t SZ = (size_t)MROWS * EDIM * 2;  // 28,311,552
  unsigned short* qbuf = (unsigned short*)(ws);
  unsigned short* kbuf = (unsigned short*)(ws + SZ);
  unsigned short* vbuf = (unsigned short*)(ws + 2 * SZ);
  unsigned short* attn = kbuf;  // kbuf dead after kv_mfma
  float* kvT  = (float*)(ws + 3 * SZ);                    // 3,145,728 B
  float* ksum = (float*)(ws + 3 * SZ + 3145728);          // 49,152 B
  unsigned short* wbf = (unsigned short*)(ws + 3 * SZ + 3145728 + 49152);
  // total ws: 92,848,128 B

  static bool attr_done = false;
  if (!attr_done) {
    (void)hipFuncSetAttribute((const void*)gemm256<0>,
                              hipFuncAttributeMaxDynamicSharedMemorySize, 131072);
    (void)hipFuncSetAttribute((const void*)gemm256<1>,
                              hipFuncAttributeMaxDynamicSharedMemorySize, 131072);
    attr_done = true;
  }

  // conv_w (2304) + transpose_q (3456) + kv/ksum zero (780) = 6540 blocks
  prep<<<dim3(6540), 256, 0, stream>>>(query, Wq, Wk, Wv, Wo, wbf, xT, kvT);

  // QKV projection: 72 row panels x 3 col panels x 3 matrices = 648 blocks
  gemm256<0><<<dim3(648), dim3(512), 131072, stream>>>(
      xT, wbf, bq, bk, bv, qbuf, kbuf, vbuf, nullptr);

  kv_mfma<<<dim3(96, 8), 256, 0, stream>>>(kbuf, vbuf, kvT, ksum);

  attn_mfma<<<dim3(L_SEQ / 128, 96), 256, 0, stream>>>(qbuf, kvT, ksum, xT, attn);

  // output projection: 72 x 3 = 216 blocks
  gemm256<1><<<dim3(216), dim3(512), 131072, stream>>>(
      attn, wbf + 3 * (size_t)EDIM * EDIM, bo, nullptr, nullptr,
      nullptr, nullptr, nullptr, out);
}

// Round 4
// 298.735 us; speedup vs baseline: 1.0067x; 1.0067x over previous
//
#include <hip/hip_runtime.h>

// CosformerAttention on MI355X (gfx950). Inputs fp32, OUTPUT fp32.
// B=8, E=768, L=48*48=2304, heads=12, d=64, n=B*h=96, M=L*B=18432.
//
// Round-11: kv_mfma's transposed LDS staging had a structural 16-way write
// bank conflict (row-stride*8 == 0 mod 32 dwords makes the oct term bank-
// invisible; true for ANY 16B-aligned stride). Fix: column-block rotation
// swizzle col' = (col + ((row>>3)&3)*8) & 31 -- thread-constant on the write
// side, static offset on the b128 read side. Also: sin/cos moved to a
// precomputed table (sct, in dead upper half of d_out) used by kv and attn.
// gemm256 byte-identical to round-9/10.

#define L_SEQ 2304
#define BATCH 8
#define EDIM 768
#define NHEAD 12
#define DHEAD 64
#define MROWS (L_SEQ * BATCH)  // 18432

typedef __attribute__((ext_vector_type(8))) short bf16x8_t;   // 8 bf16 = 4 VGPRs
typedef __attribute__((ext_vector_type(4))) float f32x4_t;

__device__ __forceinline__ float b2f(unsigned short u) {
  union { unsigned int i; float f; } x; x.i = ((unsigned int)u) << 16; return x.f;
}
__device__ __forceinline__ unsigned short f2b(float f) {
  union { float f; unsigned int i; } x; x.f = f;
  unsigned int r = x.i + 0x7FFFu + ((x.i >> 16) & 1u);  // RNE
  return (unsigned short)(r >> 16);
}

// async 16B global->LDS (gfx950; wave-uniform base + lane*16 dest contract)
#define GLOAD_LDS16(g, l)                                                     \
  __builtin_amdgcn_global_load_lds(                                           \
      (const __attribute__((address_space(1))) unsigned int*)(g),             \
      (__attribute__((address_space(3))) unsigned int*)(l), 16, 0, 0)

// ---------------------------------------------------------------------------
// Kernel 0 (merged): blocks [0,2304): conv 4 fp32 weight mats -> bf16.
//                    blocks [2304,5760): transpose query (B,E,L) -> xT bf16.
//                    blocks [5760,6540): zero kvT (3,145,728 B) + ksum (49,152 B).
//                    blocks [6540,6549): sin/cos table sct[l], l in [0,2304).
__global__ __launch_bounds__(256) void prep(
    const float* __restrict__ q,
    const float* __restrict__ W0, const float* __restrict__ W1,
    const float* __restrict__ W2, const float* __restrict__ W3,
    unsigned short* __restrict__ wbf, unsigned short* __restrict__ xT,
    float* __restrict__ kvz, float2* __restrict__ sct) {
  __shared__ float tile[64][65];
  int bx = blockIdx.x;
  int t = threadIdx.x;
  if (bx < 2304) {
    int y = bx / 576;
    const float* W = (y == 0) ? W0 : (y == 1) ? W1 : (y == 2) ? W2 : W3;
    unsigned short* d = wbf + (size_t)y * EDIM * EDIM;
    int idx = (bx - y * 576) * 256 + t;  // [0, 147456)
    float4 v = *(const float4*)(W + (size_t)idx * 4);
    ushort4 o;
    o.x = f2b(v.x); o.y = f2b(v.y); o.z = f2b(v.z); o.w = f2b(v.w);
    *(ushort4*)(d + (size_t)idx * 4) = o;
  } else if (bx < 5760) {
    int bb = bx - 2304;           // 12 x 36 x 8
    int e0 = (bb % 12) * 64;
    int l0 = ((bb / 12) % 36) * 64;
    int b = bb / 432;
    int li = t & 63, er = t >> 6;
#pragma unroll
    for (int p = 0; p < 16; p++) {
      int eo = er + p * 4;
      tile[eo][li] = q[((size_t)b * EDIM + (e0 + eo)) * L_SEQ + (l0 + li)];
    }
    __syncthreads();
    int ei = t & 63, lr = t >> 6;
#pragma unroll
    for (int p = 0; p < 16; p++) {
      int lo = lr + p * 4;
      xT[((size_t)b * L_SEQ + (l0 + lo)) * EDIM + (e0 + ei)] = f2b(tile[ei][lo]);
    }
  } else if (bx < 6540) {
    int idx = (bx - 5760) * 256 + t;  // [0, 199680) float4s
    *(float4*)(kvz + (size_t)idx * 4) = make_float4(0.f, 0.f, 0.f, 0.f);
  } else {
    int l = (bx - 6540) * 256 + t;    // [0, 2304)
    if (l < L_SEQ) {
      float sv, cv;
      sincosf(1.5707963267948966f * (float)(l + 1) / 2304.0f, &sv, &cv);
      sct[l] = make_float2(sv, cv);
    }
  }
}

// ---------------------------------------------------------------------------
// Kernel 1/4: C = A @ W^T (+bias, opt relu). 256x256 tile, BK=64, 512 thr
// (8 waves, 2Mx4N), 8-phase pipelined K-loop, 128 KiB dynamic LDS.
// (byte-identical to round-9/10; see schedule comments there)
#define ALDSO(b_, h_) ((b_) * 16384 + (h_) * 8192)
#define BLDSO(b_, h_) (32768 + (b_) * 16384 + (h_) * 8192)

#define BAR() __builtin_amdgcn_s_barrier()
#define LGKM0() asm volatile("s_waitcnt lgkmcnt(0)")
#define LGKM8() asm volatile("s_waitcnt lgkmcnt(8)")
#define VMW(N) asm volatile("s_waitcnt vmcnt(" #N ")" ::: "memory")

#define STG_A(h_, kt_, LB_)                                                          \
  {                                                                                  \
    GLOAD_LDS16(a_sb + (size_t)((h_) * 128) * EDIM + (kt_) * 64, lds + (LB_) + t * 8); \
    GLOAD_LDS16(a_sb + (size_t)((h_) * 128 + 64) * EDIM + (kt_) * 64,                \
                lds + (LB_) + 4096 + t * 8);                                         \
  }
#define STG_B(h_, kt_, LB_)                                                          \
  {                                                                                  \
    GLOAD_LDS16(b_sb + (size_t)((h_) * 128) * EDIM + (kt_) * 64, lds + (LB_) + t * 8); \
    GLOAD_LDS16(b_sb + (size_t)((h_) * 128 + 64) * EDIM + (kt_) * 64,                \
                lds + (LB_) + 4096 + t * 8);                                         \
  }

#define DS_A(SET, B_, H_)                                                            \
  _Pragma("unroll") for (int i_ = 0; i_ < 4; i_++)                                   \
  _Pragma("unroll") for (int kk_ = 0; kk_ < 2; kk_++)                                \
    SET[i_][kk_] = *(const bf16x8_t*)(lds + ALDSO(B_, H_) +                          \
                                      ((a_base + i_ * 1024 + kk_ * 32) ^ xorv));

#define DS_B(SET, B_, H_)                                                            \
  _Pragma("unroll") for (int j_ = 0; j_ < 2; j_++)                                   \
  _Pragma("unroll") for (int kk_ = 0; kk_ < 2; kk_++)                                \
    SET[j_][kk_] = *(const bf16x8_t*)(lds + BLDSO(B_, H_) +                          \
                                      ((b_base + j_ * 1024 + kk_ * 32) ^ xorv));

#define MFMAQ(ASET, BSET, AH, BH)                                                    \
  __builtin_amdgcn_s_setprio(1);                                                     \
  _Pragma("unroll") for (int i_ = 0; i_ < 4; i_++)                                   \
  _Pragma("unroll") for (int j_ = 0; j_ < 2; j_++)                                   \
  _Pragma("unroll") for (int kk_ = 0; kk_ < 2; kk_++)                                \
    acc[(AH) * 4 + i_][(BH) * 2 + j_] = __builtin_amdgcn_mfma_f32_16x16x32_bf16(     \
        ASET[i_][kk_], BSET[j_][kk_], acc[(AH) * 4 + i_][(BH) * 2 + j_], 0, 0, 0);   \
  __builtin_amdgcn_s_setprio(0);

template <int MODE>
__global__ __launch_bounds__(512, 2) void gemm256(
    const unsigned short* __restrict__ A,
    const unsigned short* __restrict__ Wall,
    const float* __restrict__ bias0, const float* __restrict__ bias1,
    const float* __restrict__ bias2,
    unsigned short* __restrict__ dst0, unsigned short* __restrict__ dst1,
    unsigned short* __restrict__ dst2,
    float* __restrict__ dstf) {
  extern __shared__ __align__(16) unsigned short lds[];

  const unsigned short* W;
  const float* bias;
  unsigned short* dst = nullptr;
  bool do_relu = false;
  int rowblk, colblk;
  {
    int nwg = (int)gridDim.x;
    int wg = ((int)blockIdx.x & 7) * (nwg >> 3) + ((int)blockIdx.x >> 3);
    if (MODE == 0) {
      rowblk = wg / 9;
      int c = wg - rowblk * 9;
      colblk = c % 3;
      int z = c / 3;
      W = Wall + (size_t)z * EDIM * EDIM;
      bias = (z == 0) ? bias0 : (z == 1) ? bias1 : bias2;
      dst = (z == 0) ? dst0 : (z == 1) ? dst1 : dst2;
      do_relu = (z < 2);
    } else {
      rowblk = wg / 3;
      colblk = wg - rowblk * 3;
      W = Wall;
      bias = bias0;
    }
  }
  const int row0 = rowblk * 256;
  const int col0 = colblk * 256;

  const int t = threadIdx.x;
  const int lane = t & 63;
  const int wave = t >> 6;
  const int wm = wave >> 2;
  const int wn = wave & 3;
  const int mrow = lane & 15;
  const int quad = lane >> 4;

  const int xorv = (mrow & 7) << 3;
  const int a_base = (wm * 64 + mrow) * 64 + quad * 8;
  const int b_base = (wn * 32 + mrow) * 64 + quad * 8;

  const int lr_s = t >> 3;
  const int k0_s = ((((t >> 3) & 7) ^ (t & 7)) << 3);
  const unsigned short* a_sb = A + (size_t)(row0 + lr_s) * EDIM + k0_s;
  const unsigned short* b_sb = W + (size_t)(col0 + lr_s) * EDIM + k0_s;

  f32x4_t acc[8][4] = {};
  bf16x8_t aA[4][2], aB[4][2], bA[2][2], bB[2][2];

  STG_A(0, 0, ALDSO(0, 0));
  STG_B(0, 0, BLDSO(0, 0));
  STG_A(1, 0, ALDSO(0, 1));
  STG_B(1, 0, BLDSO(0, 1));
  STG_A(0, 1, ALDSO(1, 0));
  STG_B(0, 1, BLDSO(1, 0));
  VMW(4);
  BAR();

#pragma unroll
  for (int i = 0; i < 6; ++i) {
    const int kt0 = 2 * i, kt1 = 2 * i + 1;
    const bool nxt = (i < 5);
    // ph1
    DS_A(aA, 0, 0);
    DS_B(bA, 0, 0);
    STG_A(1, kt1, ALDSO(1, 1));
    LGKM8();
    BAR();
    MFMAQ(aA, bA, 0, 0);
    LGKM0();
    BAR();
    // ph2
    DS_B(bB, 0, 1);
    STG_B(1, kt1, BLDSO(1, 1));
    BAR();
    MFMAQ(aA, bB, 0, 1);
    LGKM0();
    BAR();
    // ph3
    DS_A(aB, 0, 1);
    if (nxt) STG_A(0, kt0 + 2, ALDSO(0, 0));
    BAR();
    MFMAQ(aB, bA, 1, 0);
    LGKM0();
    BAR();
    // ph4
    if (nxt) STG_B(0, kt0 + 2, BLDSO(0, 0));
    BAR();
    MFMAQ(aB, bB, 1, 1);
    if (nxt) { VMW(4); } else { VMW(0); }
    BAR();
    // ph5
    DS_A(aA, 1, 0);
    DS_B(bA, 1, 0);
    if (nxt) STG_A(1, kt0 + 2, ALDSO(0, 1));
    LGKM8();
    BAR();
    MFMAQ(aA, bA, 0, 0);
    LGKM0();
    BAR();
    // ph6
    DS_B(bB, 1, 1);
    if (nxt) STG_B(1, kt0 + 2, BLDSO(0, 1));
    BAR();
    MFMAQ(aA, bB, 0, 1);
    LGKM0();
    BAR();
    // ph7
    DS_A(aB, 1, 1);
    if (nxt) STG_A(0, kt1 + 2, ALDSO(1, 0));
    BAR();
    MFMAQ(aB, bA, 1, 0);
    LGKM0();
    BAR();
    // ph8
    if (nxt) STG_B(0, kt1 + 2, BLDSO(1, 0));
    BAR();
    MFMAQ(aB, bB, 1, 1);
    if (nxt) { VMW(4); } else { VMW(0); }
    BAR();
  }

  const int bb = row0 / L_SEQ;
#pragma unroll
  for (int ti = 0; ti < 8; ti++) {
    int rbase = row0 + (ti >> 2) * 128 + wm * 64 + (ti & 3) * 16 + quad * 4;
#pragma unroll
    for (int tj = 0; tj < 4; tj++) {
      int gc = col0 + (tj >> 1) * 128 + wn * 32 + (tj & 1) * 16 + mrow;
      float bv = bias[gc];
#pragma unroll
      for (int r = 0; r < 4; r++) {
        int gr = rbase + r;
        float v = acc[ti][tj][r] + bv;
        if (MODE == 0) {
          if (do_relu) v = fmaxf(v, 0.0f);
          int ll = gr - bb * L_SEQ;
          int n = bb * NHEAD + (gc >> 6);
          dst[((size_t)n * L_SEQ + ll) * DHEAD + (gc & 63)] = f2b(v);
        } else {
          dstf[(size_t)gr * EDIM + gc] = v;  // FP32 output
        }
      }
    }
  }
}

// ---------------------------------------------------------------------------
// Kernel 2 (MFMA): kvT[n][m][j] = sum_l v[l][m]*k_[l][j]; ksum[n][j] = sum_l k_.
// LDS staging uses column-block rotation swizzle to kill the 16-way write
// bank conflict: logical (row d, col c) stored at d*ST + ((c + ((d>>3)&3)*8)&31).
// Write side: col2 is thread-constant. Read side: static block offset on b128.
__global__ __launch_bounds__(256) void kv_mfma(
    const unsigned short* __restrict__ kbuf, const unsigned short* __restrict__ vbuf,
    const float2* __restrict__ sct,
    float* __restrict__ kvT, float* __restrict__ ksum) {
  constexpr int ST = 40;  // LDS row stride (bf16)
  __shared__ __align__(16) unsigned short ksT[128 * ST];
  __shared__ __align__(16) unsigned short vsT[64 * ST];
  __shared__ float ksum_l[128];
  int n = blockIdx.x;
  int lbase = blockIdx.y * 288;
  int t = threadIdx.x;
  int lane = t & 63, wave = t >> 6;
  int mrow = lane & 15, quad = lane >> 4;

  if (t < 128) ksum_l[t] = 0.f;

  int lrd = t >> 3;   // l within slice, 0..31
  int oct = t & 7;    // d-octet
  int col2 = (lrd + ((oct & 3) << 3)) & 31;  // swizzled write column (thread-const)
  const unsigned short* kbase = kbuf + (size_t)n * L_SEQ * DHEAD + oct * 8;
  const unsigned short* vbase = vbuf + (size_t)n * L_SEQ * DHEAD + oct * 8;

  // A-frag read address (v): row rv, logical cols quad*8..+8, swizzled block
  int rv = wave * 16 + mrow;
  const unsigned short* vrd = vsT + rv * ST + (((quad + (rv >> 3)) & 3) << 3);

  f32x4_t acc[8] = {};
  float sks[8] = {}, skc[8] = {};

  for (int s = 0; s < 9; s++) {
    int l = lbase + s * 32 + lrd;
    float2 sc = sct[l];
    union { uint4 q; unsigned short u[8]; } kq, vq;
    kq.q = *(const uint4*)(kbase + (size_t)l * DHEAD);
    vq.q = *(const uint4*)(vbase + (size_t)l * DHEAD);
    __syncthreads();  // previous slice's fragment reads done (also covers init)
#pragma unroll
    for (int e = 0; e < 8; e++) {
      int d = oct * 8 + e;
      float kval = b2f(kq.u[e]);
      float a = kval * sc.x, c = kval * sc.y;
      ksT[d * ST + col2] = f2b(a);
      ksT[(64 + d) * ST + col2] = f2b(c);
      vsT[d * ST + col2] = vq.u[e];
      sks[e] += a;
      skc[e] += c;
    }
    __syncthreads();
    bf16x8_t af = *(const bf16x8_t*)(vrd);
#pragma unroll
    for (int jt = 0; jt < 8; jt++) {
      int rk = jt * 16 + mrow;
      bf16x8_t bfk = *(const bf16x8_t*)(ksT + rk * ST + (((quad + (rk >> 3)) & 3) << 3));
      acc[jt] = __builtin_amdgcn_mfma_f32_16x16x32_bf16(af, bfk, acc[jt], 0, 0, 0);
    }
  }

  // ksum reduce: per-thread f32 partials -> LDS -> global
#pragma unroll
  for (int e = 0; e < 8; e++) {
    atomicAdd(&ksum_l[oct * 8 + e], sks[e]);
    atomicAdd(&ksum_l[64 + oct * 8 + e], skc[e]);
  }
  __syncthreads();
  if (t < 128) atomicAdd(&ksum[n * 128 + t], ksum_l[t]);

  // kvT epilogue: D col = mrow -> j, row = quad*4+r -> m (within wave's m-tile)
#pragma unroll
  for (int jt = 0; jt < 8; jt++) {
#pragma unroll
    for (int r = 0; r < 4; r++) {
      int m = wave * 16 + quad * 4 + r;
      int j = jt * 16 + mrow;
      atomicAdd(&kvT[((size_t)n * 64 + m) * 128 + j], acc[jt][r]);
    }
  }
}

// ---------------------------------------------------------------------------
// Kernel 3 (MFMA): C0 = q@kv0, C1 = q@kv1; out = zs*C0 + zc*C1; fused
// residual + relayout. grid (18, 96), block 256. Bs staged from kvT rows
// (coalesced float4 + vectorized LDS writes); sin/cos from sct table.
__global__ __launch_bounds__(256) void attn_mfma(
    const unsigned short* __restrict__ qbuf, const float* __restrict__ kvT,
    const float* __restrict__ ksum, const unsigned short* __restrict__ xT,
    const float2* __restrict__ sct,
    unsigned short* __restrict__ attn) {
  __shared__ __align__(16) unsigned short As[128 * 72];
  __shared__ __align__(16) unsigned short Bs[64 * 136];
  __shared__ float ks_l[128];
  __shared__ float zs[128], zc[128];
  int l0 = blockIdx.x * 128;
  int n = blockIdx.y;
  int t = threadIdx.x;
  int lane = t & 63, wave = t >> 6;
  int mrow = lane & 15, quad = lane >> 4;
  int b = n / NHEAD, hd = n % NHEAD;

  {
    int row = t >> 1, off = (t & 1) * 32;
    const unsigned short* src = qbuf + ((size_t)n * L_SEQ + l0 + row) * DHEAD + off;
    unsigned short* d = As + row * 72 + off;
#pragma unroll
    for (int c = 0; c < 4; c++)
      *(uint4*)(d + c * 8) = *(const uint4*)(src + c * 8);
  }
  {
    int m = t >> 2, part = t & 3;  // Bs[m][j] = f2b(kvT[n][m][j]) -- coalesced
    const float* src = kvT + ((size_t)n * 64 + m) * 128 + part * 32;
    unsigned short* dBs = Bs + m * 136 + part * 32;
#pragma unroll
    for (int c = 0; c < 4; c++) {
      float4 a = *(const float4*)(src + c * 8);
      float4 bq = *(const float4*)(src + c * 8 + 4);
      ushort4 o1, o2;
      o1.x = f2b(a.x); o1.y = f2b(a.y); o1.z = f2b(a.z); o1.w = f2b(a.w);
      o2.x = f2b(bq.x); o2.y = f2b(bq.y); o2.z = f2b(bq.z); o2.w = f2b(bq.w);
      *(ushort4*)(dBs + c * 8) = o1;
      *(ushort4*)(dBs + c * 8 + 4) = o2;
    }
  }
  if (t < 128) ks_l[t] = ksum[n * 128 + t];
  __syncthreads();

  if (t < 128) {
    float d0 = 0.f, d1 = 0.f;
    const unsigned short* arow = As + t * 72;
#pragma unroll
    for (int j = 0; j < 8; j++) {
      bf16x8_t v = *(const bf16x8_t*)(arow + j * 8);
#pragma unroll
      for (int e = 0; e < 8; e++) {
        float qv = b2f((unsigned short)v[e]);
        d0 += qv * ks_l[j * 8 + e];
        d1 += qv * ks_l[64 + j * 8 + e];
      }
    }
    float2 sc = sct[l0 + t];
    float z = 1.0f / fmaxf(sc.x * d0 + sc.y * d1, 1e-6f);
    zs[t] = z * sc.x;
    zc[t] = z * sc.y;
  }
  __syncthreads();

  int wr = wave * 32;
  f32x4_t acc0[2][4] = {}, acc1[2][4] = {};
#pragma unroll
  for (int ks = 0; ks < 2; ks++) {
    bf16x8_t af[2];
#pragma unroll
    for (int ti = 0; ti < 2; ti++)
      af[ti] = *(const bf16x8_t*)(As + (wr + ti * 16 + mrow) * 72 + ks * 32 + quad * 8);
#pragma unroll
    for (int tj = 0; tj < 4; tj++) {
      bf16x8_t b0 = *(const bf16x8_t*)(Bs + (tj * 16 + mrow) * 136 + ks * 32 + quad * 8);
      bf16x8_t b1 = *(const bf16x8_t*)(Bs + (tj * 16 + mrow) * 136 + 64 + ks * 32 + quad * 8);
#pragma unroll
      for (int ti = 0; ti < 2; ti++) {
        acc0[ti][tj] = __builtin_amdgcn_mfma_f32_16x16x32_bf16(af[ti], b0, acc0[ti][tj], 0, 0, 0);
        acc1[ti][tj] = __builtin_amdgcn_mfma_f32_16x16x32_bf16(af[ti], b1, acc1[ti][tj], 0, 0, 0);
      }
    }
  }

#pragma unroll
  for (int ti = 0; ti < 2; ti++) {
#pragma unroll
    for (int tj = 0; tj < 4; tj++) {
      int m = tj * 16 + mrow;
#pragma unroll
      for (int r = 0; r < 4; r++) {
        int row = wr + ti * 16 + quad * 4 + r;
        int l = l0 + row;
        float ov = zs[row] * acc0[ti][tj][r] + zc[row] * acc1[ti][tj][r];
        float xv = b2f(xT[((size_t)b * L_SEQ + l) * EDIM + hd * DHEAD + m]);
        attn[((size_t)l * BATCH + b) * EDIM + hd * DHEAD + m] = f2b(xv + ov);
      }
    }
  }
}

// ---------------------------------------------------------------------------
extern "C" void kernel_launch(void* const* d_in, const int* in_sizes, int n_in,
                              void* d_out, int out_size, void* d_ws, size_t ws_size,
                              hipStream_t stream) {
  const float* query = (const float*)d_in[0];
  const float* Wq = (const float*)d_in[1];
  const float* bq = (const float*)d_in[2];
  const float* Wk = (const float*)d_in[3];
  const float* bk = (const float*)d_in[4];
  const float* Wv = (const float*)d_in[5];
  const float* bv = (const float*)d_in[6];
  const float* Wo = (const float*)d_in[7];
  const float* bo = (const float*)d_in[8];
  float* out = (float*)d_out;  // fp32 output

  unsigned short* xT = (unsigned short*)d_out;  // bf16 staging inside d_out

  char* ws = (char*)d_ws;
  const size_t SZ = (size_t)MROWS * EDIM * 2;  // 28,311,552
  unsigned short* qbuf = (unsigned short*)(ws);
  unsigned short* kbuf = (unsigned short*)(ws + SZ);
  unsigned short* vbuf = (unsigned short*)(ws + 2 * SZ);
  unsigned short* attn = kbuf;  // kbuf dead after kv_mfma
  float* kvT  = (float*)(ws + 3 * SZ);                    // 3,145,728 B
  float* ksum = (float*)(ws + 3 * SZ + 3145728);          // 49,152 B
  unsigned short* wbf = (unsigned short*)(ws + 3 * SZ + 3145728 + 49152);
  // total ws: 92,848,128 B

  // sin/cos table in the dead upper half of d_out (overwritten only by the
  // final gemm256<1> output store, after its last use in attn_mfma).
  float2* sct = (float2*)((char*)d_out + SZ);

  static bool attr_done = false;
  if (!attr_done) {
    (void)hipFuncSetAttribute((const void*)gemm256<0>,
                              hipFuncAttributeMaxDynamicSharedMemorySize, 131072);
    (void)hipFuncSetAttribute((const void*)gemm256<1>,
                              hipFuncAttributeMaxDynamicSharedMemorySize, 131072);
    attr_done = true;
  }

  // conv_w (2304) + transpose_q (3456) + kv/ksum zero (780) + sct (9) = 6549
  prep<<<dim3(6549), 256, 0, stream>>>(query, Wq, Wk, Wv, Wo, wbf, xT, kvT, sct);

  // QKV projection: 72 row panels x 3 col panels x 3 matrices = 648 blocks
  gemm256<0><<<dim3(648), dim3(512), 131072, stream>>>(
      xT, wbf, bq, bk, bv, qbuf, kbuf, vbuf, nullptr);

  kv_mfma<<<dim3(96, 8), 256, 0, stream>>>(kbuf, vbuf, sct, kvT, ksum);

  attn_mfma<<<dim3(L_SEQ / 128, 96), 256, 0, stream>>>(qbuf, kvT, ksum, xT, sct, attn);

  // output projection: 72 x 3 = 216 blocks
  gemm256<1><<<dim3(216), dim3(512), 131072, stream>>>(
      attn, wbf + 3 * (size_t)EDIM * EDIM, bo, nullptr, nullptr,
      nullptr, nullptr, nullptr, out);
}